// Round 14
// baseline (222.101 us; speedup 1.0000x reference)
//
#include <hip/hip_runtime.h>
#include <hip/hip_bf16.h>

#define B_ 4
#define S_ 2048
#define E_ 1024
#define H_ 16
#define HD_ 64
#define QS 3072   // fused QKV row stride

typedef __attribute__((ext_vector_type(8))) short bf16x8;
typedef __attribute__((ext_vector_type(4))) float f32x4;

__device__ __forceinline__ float b2f(unsigned short u) {
    union { unsigned u; float f; } v; v.u = ((unsigned)u) << 16; return v.f;
}
__device__ __forceinline__ unsigned short f2b(float f) {
    union { float f; unsigned u; } v; v.f = f;
    unsigned lsb = (v.u >> 16) & 1u;
    v.u += 0x7fffu + lsb;
    return (unsigned short)(v.u >> 16);
}
__device__ __forceinline__ unsigned cvtpk_bf16(float lo, float hi) {
    unsigned r;
    asm("v_cvt_pk_bf16_f32 %0, %1, %2" : "=v"(r) : "v"(lo), "v"(hi));
    return r;
}

// direct global -> LDS async copy, 16B per lane (linear dest = base + lane*16)
typedef const __attribute__((address_space(1))) unsigned glb_u32;
typedef __attribute__((address_space(3))) unsigned lds_u32;
__device__ __forceinline__ void gl_lds16(const unsigned short* g,
                                         unsigned short* l) {
    __builtin_amdgcn_global_load_lds((glb_u32*)g, (lds_u32*)l, 16, 0, 0);
}

// ---------------- elementwise f32 -> bf16 ----------------
__global__ void cvt_f32_to_bf16(const float* __restrict__ in,
                                unsigned short* __restrict__ out, int n8) {
    int i = blockIdx.x * blockDim.x + threadIdx.x;
    if (i >= n8) return;
    const float4* p = (const float4*)(in + (size_t)i * 8);
    float4 a = p[0], b = p[1];
    bf16x8 o;
    o[0] = (short)f2b(a.x); o[1] = (short)f2b(a.y);
    o[2] = (short)f2b(a.z); o[3] = (short)f2b(a.w);
    o[4] = (short)f2b(b.x); o[5] = (short)f2b(b.y);
    o[6] = (short)f2b(b.z); o[7] = (short)f2b(b.w);
    *(bf16x8*)(out + (size_t)i * 8) = o;
}

// ---------------- 4x W[K][N] f32 -> Wt[N][K] bf16 (one launch) ------------
__global__ void transpose_cvt4(const float* __restrict__ W0,
                               const float* __restrict__ W1,
                               const float* __restrict__ W2,
                               const float* __restrict__ W3,
                               unsigned short* __restrict__ Wqkv,
                               unsigned short* __restrict__ Wto) {
    __shared__ float tile[32][33];
    int z = blockIdx.z;
    const float* W = (z == 0) ? W0 : (z == 1) ? W1 : (z == 2) ? W2 : W3;
    unsigned short* Wt = (z < 3) ? Wqkv + (size_t)z * 1024 * E_ : Wto;
    int tx = threadIdx.x, ty = threadIdx.y;  // (32, 8)
    int x0 = blockIdx.x * 32, y0 = blockIdx.y * 32;
#pragma unroll
    for (int j = 0; j < 32; j += 8)
        tile[ty + j][tx] = W[(size_t)(y0 + ty + j) * E_ + x0 + tx];
    __syncthreads();
#pragma unroll
    for (int j = 0; j < 32; j += 8)
        Wt[(size_t)(x0 + ty + j) * E_ + y0 + tx] = f2b(tile[tx][ty + j]);
}

// ---------------- GEMM: C[M,N] = A[M,K] @ Bt[N,K]^T + bias (bf16 out) -----
// bias selected among b0/b1/b2 by col>>10 (fused-QKV support)
// XCD-aware block swizzle: ti = (bid%8)*chunk + bid/8 (grid %8 == 0)
#define BM 128
#define BN 128
#define BK 32

__global__ __launch_bounds__(256) void gemm_bt(
        const unsigned short* __restrict__ A,
        const unsigned short* __restrict__ Bt,
        const float* __restrict__ b0, const float* __restrict__ b1,
        const float* __restrict__ b2,
        unsigned short* __restrict__ Cb,
        int M, int N, int K) {
    __shared__ unsigned short As[BM][BK];
    __shared__ unsigned short Bs[BN][BK];
    int t = threadIdx.x;
    int lane = t & 63, wid = t >> 6;
    int wr = wid >> 1, wc = wid & 1;
    // XCD swizzle (nwg = gridDim.x*gridDim.y, divisible by 8)
    int nwg = gridDim.x * gridDim.y;
    int bid = blockIdx.y * gridDim.x + blockIdx.x;
    int ti = (bid & 7) * (nwg >> 3) + (bid >> 3);
    int bx = ti % gridDim.x, by = ti / gridDim.x;
    const int row = t >> 2, kc = (t & 3) << 3;
    const unsigned short* ga0 = A + (size_t)(by * BM + row) * K + kc;
    const unsigned short* gb0 = Bt + (size_t)(bx * BN + row) * K + kc;
    unsigned short* la0 = &As[0][0] + (size_t)t * 8;
    unsigned short* lb0 = &Bs[0][0] + (size_t)t * 8;
    const size_t step64 = (size_t)64 * K;

    f32x4 acc[4][4] = {};

    for (int ko = 0; ko < K; ko += BK) {
        gl_lds16(ga0 + ko, la0);
        gl_lds16(ga0 + ko + step64, la0 + 2048);
        gl_lds16(gb0 + ko, lb0);
        gl_lds16(gb0 + ko + step64, lb0 + 2048);
        __syncthreads();   // drains vmcnt(0) -> tiles resident
        int kg = (lane >> 4) << 3;  // k offset 0,8,16,24
        bf16x8 af[4], bfr[4];
#pragma unroll
        for (int i = 0; i < 4; ++i) {
            af[i]  = *(const bf16x8*)&As[wr * 64 + i * 16 + (lane & 15)][kg];
            bfr[i] = *(const bf16x8*)&Bs[wc * 64 + i * 16 + (lane & 15)][kg];
        }
#pragma unroll
        for (int i = 0; i < 4; ++i)
#pragma unroll
            for (int j = 0; j < 4; ++j)
                acc[i][j] = __builtin_amdgcn_mfma_f32_16x16x32_bf16(
                    af[i], bfr[j], acc[i][j], 0, 0, 0);
        __syncthreads();
    }

#pragma unroll
    for (int i = 0; i < 4; ++i) {
        int row0 = by * BM + wr * 64 + i * 16 + ((lane >> 4) << 2);
#pragma unroll
        for (int j = 0; j < 4; ++j) {
            int col = bx * BN + wc * 64 + j * 16 + (lane & 15);
            const float* bp = (col < 1024) ? b0 : ((col < 2048) ? b1 : b2);
            float bv = bp[col & 1023];
#pragma unroll
            for (int r = 0; r < 4; ++r) {
                int rr = row0 + r;
                Cb[(size_t)rr * N + col] = f2b(acc[i][j][r] + bv);
            }
        }
    }
}

// ---------------- output GEMM: BM=64 tile (1024 blocks -> 4+/CU) ----------
__global__ __launch_bounds__(256) void gemm_bt_out(
        const unsigned short* __restrict__ A,
        const unsigned short* __restrict__ Bt,
        const float* __restrict__ bias,
        float* __restrict__ Cf, int M, int N, int K) {
    __shared__ unsigned short As[64][BK];
    __shared__ unsigned short Bs[BN][BK];
    int t = threadIdx.x;
    int lane = t & 63, wid = t >> 6;
    int wr = wid >> 1, wc = wid & 1;   // wave: 32 rows x 64 cols
    int nwg = gridDim.x * gridDim.y;
    int bid = blockIdx.y * gridDim.x + blockIdx.x;
    int ti = (bid & 7) * (nwg >> 3) + (bid >> 3);
    int bx = ti % gridDim.x, by = ti / gridDim.x;
    const int row = t >> 2, kc = (t & 3) << 3;
    const unsigned short* ga0 = A + (size_t)(by * 64 + row) * K + kc;
    const unsigned short* gb0 = Bt + (size_t)(bx * BN + row) * K + kc;
    unsigned short* la0 = &As[0][0] + (size_t)t * 8;
    unsigned short* lb0 = &Bs[0][0] + (size_t)t * 8;
    const size_t step64 = (size_t)64 * K;

    f32x4 acc[2][4] = {};

    for (int ko = 0; ko < K; ko += BK) {
        gl_lds16(ga0 + ko, la0);
        gl_lds16(gb0 + ko, lb0);
        gl_lds16(gb0 + ko + step64, lb0 + 2048);
        __syncthreads();
        int kg = (lane >> 4) << 3;
        bf16x8 af[2], bfr[4];
#pragma unroll
        for (int i = 0; i < 2; ++i)
            af[i] = *(const bf16x8*)&As[wr * 32 + i * 16 + (lane & 15)][kg];
#pragma unroll
        for (int j = 0; j < 4; ++j)
            bfr[j] = *(const bf16x8*)&Bs[wc * 64 + j * 16 + (lane & 15)][kg];
#pragma unroll
        for (int i = 0; i < 2; ++i)
#pragma unroll
            for (int j = 0; j < 4; ++j)
                acc[i][j] = __builtin_amdgcn_mfma_f32_16x16x32_bf16(
                    af[i], bfr[j], acc[i][j], 0, 0, 0);
        __syncthreads();
    }

#pragma unroll
    for (int i = 0; i < 2; ++i) {
        int row0 = by * 64 + wr * 32 + i * 16 + ((lane >> 4) << 2);
#pragma unroll
        for (int j = 0; j < 4; ++j) {
            int col = bx * BN + wc * 64 + j * 16 + (lane & 15);
            float bv = bias[col];
#pragma unroll
            for (int r = 0; r < 4; ++r)
                Cf[(size_t)(row0 + r) * N + col] = acc[i][j][r] + bv;
        }
    }
}

// ---------------- causal flash attention, swapped-QK^T MFMA ----------------
// Uniform sequential pairing: q-tile = 64 rows (wave owns 16), block y
// processes units qt=31-y THEN qt=y sequentially (registers reused).
// Every block = exactly 33 compute-tiles -> no causal tail imbalance.
// Per-unit: proven r10/r13 pipeline (2-phase dbuf, swapped QK^T, in-reg
// softmax w/ defer-max, P via per-wave LDS, PV 16x16x32).
#define KVBLK 64

__global__ __launch_bounds__(256) void attn_mfma(
        const unsigned short* __restrict__ QKV,
        unsigned short* __restrict__ Yb) {
    __shared__ unsigned short Ks[2][KVBLK][64];  // [key][d], col ^= (key&7)<<3
    __shared__ unsigned short Vt[2][64][KVBLK];  // [d][key], col ^= sig(d)<<3
    __shared__ unsigned short Pl[4][16][64];     // per-wave P[q16][key]

    int t = threadIdx.x;
    int lane = t & 63, wid = t >> 6;
    int l15 = lane & 15, lg = lane >> 4;
    int bh = blockIdx.x;
    int b = bh >> 4, h = bh & 15;
    int vidx = lg << 4;                    // bpermute byte base: lane lg*4+r

    // K staging geometry (gl_lds): dest byte = t*16 -> row t>>3, chunk t&7;
    // source chunk = (t&7) ^ (row&7)  (inverse of read-side XOR swizzle)
    const int kk1 = t >> 3, kk2 = 32 + kk1;
    const int kg1 = ((t & 7) ^ (kk1 & 7)) << 3;   // element offset
    const int kg2 = ((t & 7) ^ (kk2 & 7)) << 3;
    // V staging geometry (reg): key = t>>2, d-base = (t&3)*16
    const int vkey = t >> 2, vc4 = (t & 3) << 4;
    const float qscale = 0.125f * 1.44269504f;   // 1/sqrt(64) * log2(e)

    const unsigned short* kvbase = QKV + ((size_t)b * S_) * QS + 1024 + h * 64;

    int cur = 0;
#pragma unroll 1
    for (int uu = 0; uu < 2; ++uu) {
        int qt = uu ? blockIdx.y : (31 - blockIdx.y);   // heavy unit first
        int qbase = qt * 64 + wid * 16;

        // ---- Q fragments for this unit ----
        bf16x8 qf[2];
#pragma unroll
        for (int ks = 0; ks < 2; ++ks) {
            int row = qbase + l15;
            bf16x8 v = *(const bf16x8*)&QKV[((size_t)(b * S_ + row)) * QS +
                                            h * 64 + ks * 32 + lg * 8];
#pragma unroll
            for (int e = 0; e < 8; ++e)
                qf[ks][e] = (short)f2b(b2f((unsigned short)v[e]) * qscale);
        }

        f32x4 yacc[4] = {};
        float m_ = -1e30f, l_ = 0.f;
        int ntiles = qt + 1;

        // ---- prologue: stage unit's tile 0 into buffer cur ----
        {
            gl_lds16(kvbase + (size_t)kk1 * QS + kg1,
                     &Ks[cur][0][0] + (size_t)t * 8);
            gl_lds16(kvbase + (size_t)kk2 * QS + kg2,
                     &Ks[cur][0][0] + 2048 + (size_t)t * 8);
            const unsigned short* vsrc =
                kvbase + 1024 + (size_t)vkey * QS + vc4;
            bf16x8 v0 = *(const bf16x8*)vsrc;
            bf16x8 v1 = *(const bf16x8*)(vsrc + 8);
#pragma unroll
            for (int e = 0; e < 8; ++e) {
                int d0 = vc4 + e, d1 = vc4 + 8 + e;
                int s0 = (d0 & 7) ^ ((d0 >> 3) & 7);
                int s1 = (d1 & 7) ^ ((d1 >> 3) & 7);
                Vt[cur][d0][vkey ^ (s0 << 3)] = (unsigned short)v0[e];
                Vt[cur][d1][vkey ^ (s1 << 3)] = (unsigned short)v1[e];
            }
        }
        __syncthreads();   // drains gl_lds (vmcnt) + ds writes

        for (int kt = 0; kt < ntiles; ++kt) {
            int k0 = kt * KVBLK;
            bool pre = (kt + 1 < ntiles);
            bf16x8 nv0, nv1;
            // ---- issue next tile's loads (latency hides under compute) ----
            if (pre) {
                const unsigned short* kb = kvbase + (size_t)(k0 + KVBLK) * QS;
                unsigned short* ld = &Ks[cur ^ 1][0][0];
                gl_lds16(kb + (size_t)kk1 * QS + kg1, ld + (size_t)t * 8);
                gl_lds16(kb + (size_t)kk2 * QS + kg2,
                         ld + 2048 + (size_t)t * 8);
                const unsigned short* vsrc =
                    kb + 1024 + (size_t)vkey * QS + vc4;
                nv0 = *(const bf16x8*)vsrc;
                nv1 = *(const bf16x8*)(vsrc + 8);
            }

            if (k0 <= qbase + 15) {          // wave not fully masked
                bool boundary = (k0 + KVBLK - 1 > qbase);
                // ---- S^T = K Q^T : rows key (A side), cols q (B side) ----
                f32x4 sacc[4] = {};
#pragma unroll
                for (int ks = 0; ks < 2; ++ks) {
                    bf16x8 kf[4];
#pragma unroll
                    for (int n = 0; n < 4; ++n)
                        kf[n] = *(const bf16x8*)&Ks[cur][n * 16 + l15]
                                  [(ks * 32 + lg * 8) ^ ((l15 & 7) << 3)];
#pragma unroll
                    for (int n = 0; n < 4; ++n)
                        sacc[n] = __builtin_amdgcn_mfma_f32_16x16x32_bf16(
                            kf[n], qf[ks], sacc[n], 0, 0, 0);
                }

                int qv = qbase + l15;        // this lane's q row
                if (boundary) {
#pragma unroll
                    for (int n = 0; n < 4; ++n)
#pragma unroll
                        for (int r = 0; r < 4; ++r)
                            if (k0 + n * 16 + lg * 4 + r > qv)
                                sacc[n][r] = -3e38f;
                }
                // ---- online softmax over keys (in-reg + 2 shfl) ----
                float pm = -3e38f;
#pragma unroll
                for (int n = 0; n < 4; ++n)
#pragma unroll
                    for (int r = 0; r < 4; ++r)
                        pm = fmaxf(pm, sacc[n][r]);
                pm = fmaxf(pm, __shfl_xor(pm, 16));
                pm = fmaxf(pm, __shfl_xor(pm, 32));
                float mo = m_;
                float mn = mo;
                bool need = __any(pm > mo + 8.0f);   // defer-max THR=8 (exp2)
                if (need) {
                    mn = fmaxf(mo, pm);
                    float corr = __builtin_exp2f(mo - mn);
                    m_ = mn;
                    l_ *= corr;
                    int ci = __float_as_int(corr);
#pragma unroll
                    for (int r = 0; r < 4; ++r) {
                        float cq = __int_as_float(
                            __builtin_amdgcn_ds_bpermute(vidx + 4 * r, ci));
#pragma unroll
                        for (int n = 0; n < 4; ++n) yacc[n][r] *= cq;
                    }
                }
                float rs = 0.f;
#pragma unroll
                for (int n = 0; n < 4; ++n)
#pragma unroll
                    for (int r = 0; r < 4; ++r) {
                        float p = __builtin_exp2f(sacc[n][r] - mn);
                        sacc[n][r] = p;
                        rs += p;
                    }
                rs += __shfl_xor(rs, 16);
                rs += __shfl_xor(rs, 32);
                l_ += rs;
                // ---- pack P pairs -> per-wave LDS (row q=l15) ----
#pragma unroll
                for (int n = 0; n < 4; ++n)
#pragma unroll
                    for (int j = 0; j < 2; ++j) {
                        unsigned u = cvtpk_bf16(sacc[n][2 * j],
                                                sacc[n][2 * j + 1]);
                        int col = (n * 16 + lg * 4 + 2 * j) ^ ((l15 & 7) << 3);
                        *(unsigned*)&Pl[wid][l15][col] = u;
                    }
                // ---- Y += P V  (16x16x32, A = P from LDS, B = Vt) ----
#pragma unroll
                for (int ks = 0; ks < 2; ++ks) {
                    bf16x8 pa, vf[4];
                    pa = *(const bf16x8*)&Pl[wid][l15]
                           [(ks * 32 + lg * 8) ^ ((l15 & 7) << 3)];
#pragma unroll
                    for (int nd = 0; nd < 4; ++nd) {
                        int d = nd * 16 + l15;
                        int sig = (d & 7) ^ ((d >> 3) & 7);
                        vf[nd] = *(const bf16x8*)&Vt[cur][d]
                                   [(ks * 32 + lg * 8) ^ (sig << 3)];
                    }
#pragma unroll
                    for (int nd = 0; nd < 4; ++nd)
                        yacc[nd] = __builtin_amdgcn_mfma_f32_16x16x32_bf16(
                            pa, vf[nd], yacc[nd], 0, 0, 0);
                }
            }

            // ---- write prefetched V into next buffer (after compute) ----
            if (pre) {
#pragma unroll
                for (int e = 0; e < 8; ++e) {
                    int d0 = vc4 + e, d1 = vc4 + 8 + e;
                    int s0 = (d0 & 7) ^ ((d0 >> 3) & 7);
                    int s1 = (d1 & 7) ^ ((d1 >> 3) & 7);
                    Vt[cur ^ 1][d0][vkey ^ (s0 << 3)] = (unsigned short)nv0[e];
                    Vt[cur ^ 1][d1][vkey ^ (s1 << 3)] = (unsigned short)nv1[e];
                }
            }
            __syncthreads();   // one barrier per tile: drains gl_lds + V writes
            cur ^= 1;
        }

        // ---- epilogue: write Y / l for this unit ----
        {
            float inv = 1.f / l_;
            int ii = __float_as_int(inv);
            float iv[4];
#pragma unroll
            for (int r = 0; r < 4; ++r)
                iv[r] = __int_as_float(
                    __builtin_amdgcn_ds_bpermute(vidx + 4 * r, ii));
#pragma unroll
            for (int n = 0; n < 4; ++n)
#pragma unroll
                for (int r = 0; r < 4; ++r) {
                    int row = qbase + lg * 4 + r;
                    int d = n * 16 + l15;
                    Yb[((size_t)(b * S_ + row)) * E_ + h * 64 + d] =
                        f2b(yacc[n][r] * iv[r]);
                }
        }
    }
}

extern "C" void kernel_launch(void* const* d_in, const int* in_sizes, int n_in,
                              void* d_out, int out_size, void* d_ws, size_t ws_size,
                              hipStream_t stream) {
    const float* x  = (const float*)d_in[0];
    const float* Wq = (const float*)d_in[1];
    const float* bq = (const float*)d_in[2];
    const float* Wk = (const float*)d_in[3];
    const float* bk = (const float*)d_in[4];
    const float* Wv = (const float*)d_in[5];
    const float* bv = (const float*)d_in[6];
    const float* Wo = (const float*)d_in[7];
    const float* bo = (const float*)d_in[8];

    char* ws = (char*)d_ws;
    const size_t M = (size_t)B_ * S_;  // 8192
    unsigned short* xb   = (unsigned short*)ws;                    // 16 MB (reused as Y)
    unsigned short* QKVb = (unsigned short*)(ws + (16ull << 20));  // 48 MB
    unsigned short* Wqkv = (unsigned short*)(ws + (64ull << 20));  // 6 MB
    unsigned short* Wto  = (unsigned short*)(ws + (70ull << 20));  // 2 MB
    unsigned short* Yb   = xb;                                     // reuse

    int n8 = (int)(M * E_ / 8);
    cvt_f32_to_bf16<<<(n8 + 255) / 256, 256, 0, stream>>>(x, xb, n8);

    dim3 tb(32, 8), tg(32, 32, 4);
    transpose_cvt4<<<tg, tb, 0, stream>>>(Wq, Wk, Wv, Wo, Wqkv, Wto);

    // fused QKV projection: C[8192][3072]
    dim3 gq(QS / BN, M / BM);  // (24, 64) = 1536 blocks
    gemm_bt<<<gq, 256, 0, stream>>>(xb, Wqkv, bq, bk, bv, QKVb,
                                    (int)M, QS, E_);

    // attention: 64-row q-tiles, sequential pairing (y, 31-y) -> uniform 33
    dim3 ag(B_ * H_, 16);  // (64, 16) = 1024 blocks
    attn_mfma<<<ag, 256, 0, stream>>>(QKVb, Yb);

    // output projection: BM=64 tiles -> 1024 blocks
    dim3 gg(E_ / BN, M / 64);  // (8, 128)
    gemm_bt_out<<<gg, 256, 0, stream>>>(Yb, Wto, bo, (float*)d_out,
                                        (int)M, E_, E_);
}

// Round 15
// 209.232 us; speedup vs baseline: 1.0615x; 1.0615x over previous
//
#include <hip/hip_runtime.h>
#include <hip/hip_bf16.h>

#define B_ 4
#define S_ 2048
#define E_ 1024
#define H_ 16
#define HD_ 64
#define QS 3072   // fused QKV row stride

typedef __attribute__((ext_vector_type(8))) short bf16x8;
typedef __attribute__((ext_vector_type(4))) float f32x4;

__device__ __forceinline__ float b2f(unsigned short u) {
    union { unsigned u; float f; } v; v.u = ((unsigned)u) << 16; return v.f;
}
__device__ __forceinline__ unsigned short f2b(float f) {
    union { float f; unsigned u; } v; v.f = f;
    unsigned lsb = (v.u >> 16) & 1u;
    v.u += 0x7fffu + lsb;
    return (unsigned short)(v.u >> 16);
}
__device__ __forceinline__ unsigned cvtpk_bf16(float lo, float hi) {
    unsigned r;
    asm("v_cvt_pk_bf16_f32 %0, %1, %2" : "=v"(r) : "v"(lo), "v"(hi));
    return r;
}

// direct global -> LDS async copy, 16B per lane (linear dest = base + lane*16)
typedef const __attribute__((address_space(1))) unsigned glb_u32;
typedef __attribute__((address_space(3))) unsigned lds_u32;
__device__ __forceinline__ void gl_lds16(const unsigned short* g,
                                         unsigned short* l) {
    __builtin_amdgcn_global_load_lds((glb_u32*)g, (lds_u32*)l, 16, 0, 0);
}

// ---------------- elementwise f32 -> bf16 ----------------
__global__ void cvt_f32_to_bf16(const float* __restrict__ in,
                                unsigned short* __restrict__ out, int n8) {
    int i = blockIdx.x * blockDim.x + threadIdx.x;
    if (i >= n8) return;
    const float4* p = (const float4*)(in + (size_t)i * 8);
    float4 a = p[0], b = p[1];
    bf16x8 o;
    o[0] = (short)f2b(a.x); o[1] = (short)f2b(a.y);
    o[2] = (short)f2b(a.z); o[3] = (short)f2b(a.w);
    o[4] = (short)f2b(b.x); o[5] = (short)f2b(b.y);
    o[6] = (short)f2b(b.z); o[7] = (short)f2b(b.w);
    *(bf16x8*)(out + (size_t)i * 8) = o;
}

// ---------------- 4x W[K][N] f32 -> Wt[N][K] bf16 (one launch) ------------
__global__ void transpose_cvt4(const float* __restrict__ W0,
                               const float* __restrict__ W1,
                               const float* __restrict__ W2,
                               const float* __restrict__ W3,
                               unsigned short* __restrict__ Wqkv,
                               unsigned short* __restrict__ Wto) {
    __shared__ float tile[32][33];
    int z = blockIdx.z;
    const float* W = (z == 0) ? W0 : (z == 1) ? W1 : (z == 2) ? W2 : W3;
    unsigned short* Wt = (z < 3) ? Wqkv + (size_t)z * 1024 * E_ : Wto;
    int tx = threadIdx.x, ty = threadIdx.y;  // (32, 8)
    int x0 = blockIdx.x * 32, y0 = blockIdx.y * 32;
#pragma unroll
    for (int j = 0; j < 32; j += 8)
        tile[ty + j][tx] = W[(size_t)(y0 + ty + j) * E_ + x0 + tx];
    __syncthreads();
#pragma unroll
    for (int j = 0; j < 32; j += 8)
        Wt[(size_t)(x0 + ty + j) * E_ + y0 + tx] = f2b(tile[tx][ty + j]);
}

// ---------------- GEMM: C[M,N] = A[M,K] @ Bt[N,K]^T + bias (bf16 out) -----
// bias selected among b0/b1/b2 by col>>10 (fused-QKV support)
// XCD-aware block swizzle: ti = (bid%8)*chunk + bid/8 (grid %8 == 0)
#define BM 128
#define BN 128
#define BK 32

__global__ __launch_bounds__(256) void gemm_bt(
        const unsigned short* __restrict__ A,
        const unsigned short* __restrict__ Bt,
        const float* __restrict__ b0, const float* __restrict__ b1,
        const float* __restrict__ b2,
        unsigned short* __restrict__ Cb,
        int M, int N, int K) {
    __shared__ unsigned short As[BM][BK];
    __shared__ unsigned short Bs[BN][BK];
    int t = threadIdx.x;
    int lane = t & 63, wid = t >> 6;
    int wr = wid >> 1, wc = wid & 1;
    // XCD swizzle (nwg = gridDim.x*gridDim.y, divisible by 8)
    int nwg = gridDim.x * gridDim.y;
    int bid = blockIdx.y * gridDim.x + blockIdx.x;
    int ti = (bid & 7) * (nwg >> 3) + (bid >> 3);
    int bx = ti % gridDim.x, by = ti / gridDim.x;
    const int row = t >> 2, kc = (t & 3) << 3;
    const unsigned short* ga0 = A + (size_t)(by * BM + row) * K + kc;
    const unsigned short* gb0 = Bt + (size_t)(bx * BN + row) * K + kc;
    unsigned short* la0 = &As[0][0] + (size_t)t * 8;
    unsigned short* lb0 = &Bs[0][0] + (size_t)t * 8;
    const size_t step64 = (size_t)64 * K;

    f32x4 acc[4][4] = {};

    for (int ko = 0; ko < K; ko += BK) {
        gl_lds16(ga0 + ko, la0);
        gl_lds16(ga0 + ko + step64, la0 + 2048);
        gl_lds16(gb0 + ko, lb0);
        gl_lds16(gb0 + ko + step64, lb0 + 2048);
        __syncthreads();   // drains vmcnt(0) -> tiles resident
        int kg = (lane >> 4) << 3;  // k offset 0,8,16,24
        bf16x8 af[4], bfr[4];
#pragma unroll
        for (int i = 0; i < 4; ++i) {
            af[i]  = *(const bf16x8*)&As[wr * 64 + i * 16 + (lane & 15)][kg];
            bfr[i] = *(const bf16x8*)&Bs[wc * 64 + i * 16 + (lane & 15)][kg];
        }
#pragma unroll
        for (int i = 0; i < 4; ++i)
#pragma unroll
            for (int j = 0; j < 4; ++j)
                acc[i][j] = __builtin_amdgcn_mfma_f32_16x16x32_bf16(
                    af[i], bfr[j], acc[i][j], 0, 0, 0);
        __syncthreads();
    }

#pragma unroll
    for (int i = 0; i < 4; ++i) {
        int row0 = by * BM + wr * 64 + i * 16 + ((lane >> 4) << 2);
#pragma unroll
        for (int j = 0; j < 4; ++j) {
            int col = bx * BN + wc * 64 + j * 16 + (lane & 15);
            const float* bp = (col < 1024) ? b0 : ((col < 2048) ? b1 : b2);
            float bv = bp[col & 1023];
#pragma unroll
            for (int r = 0; r < 4; ++r) {
                int rr = row0 + r;
                Cb[(size_t)rr * N + col] = f2b(acc[i][j][r] + bv);
            }
        }
    }
}

// ---------------- output GEMM: BM=64 tile (1024 blocks -> 4+/CU) ----------
__global__ __launch_bounds__(256) void gemm_bt_out(
        const unsigned short* __restrict__ A,
        const unsigned short* __restrict__ Bt,
        const float* __restrict__ bias,
        float* __restrict__ Cf, int M, int N, int K) {
    __shared__ unsigned short As[64][BK];
    __shared__ unsigned short Bs[BN][BK];
    int t = threadIdx.x;
    int lane = t & 63, wid = t >> 6;
    int wr = wid >> 1, wc = wid & 1;   // wave: 32 rows x 64 cols
    int nwg = gridDim.x * gridDim.y;
    int bid = blockIdx.y * gridDim.x + blockIdx.x;
    int ti = (bid & 7) * (nwg >> 3) + (bid >> 3);
    int bx = ti % gridDim.x, by = ti / gridDim.x;
    const int row = t >> 2, kc = (t & 3) << 3;
    const unsigned short* ga0 = A + (size_t)(by * 64 + row) * K + kc;
    const unsigned short* gb0 = Bt + (size_t)(bx * BN + row) * K + kc;
    unsigned short* la0 = &As[0][0] + (size_t)t * 8;
    unsigned short* lb0 = &Bs[0][0] + (size_t)t * 8;
    const size_t step64 = (size_t)64 * K;

    f32x4 acc[2][4] = {};

    for (int ko = 0; ko < K; ko += BK) {
        gl_lds16(ga0 + ko, la0);
        gl_lds16(gb0 + ko, lb0);
        gl_lds16(gb0 + ko + step64, lb0 + 2048);
        __syncthreads();
        int kg = (lane >> 4) << 3;
        bf16x8 af[2], bfr[4];
#pragma unroll
        for (int i = 0; i < 2; ++i)
            af[i] = *(const bf16x8*)&As[wr * 32 + i * 16 + (lane & 15)][kg];
#pragma unroll
        for (int j = 0; j < 4; ++j)
            bfr[j] = *(const bf16x8*)&Bs[wc * 64 + j * 16 + (lane & 15)][kg];
#pragma unroll
        for (int i = 0; i < 2; ++i)
#pragma unroll
            for (int j = 0; j < 4; ++j)
                acc[i][j] = __builtin_amdgcn_mfma_f32_16x16x32_bf16(
                    af[i], bfr[j], acc[i][j], 0, 0, 0);
        __syncthreads();
    }

#pragma unroll
    for (int i = 0; i < 2; ++i) {
        int row0 = by * 64 + wr * 32 + i * 16 + ((lane >> 4) << 2);
#pragma unroll
        for (int j = 0; j < 4; ++j) {
            int col = bx * BN + wc * 64 + j * 16 + (lane & 15);
            float bv = bias[col];
#pragma unroll
            for (int r = 0; r < 4; ++r)
                Cf[(size_t)(row0 + r) * N + col] = acc[i][j][r] + bv;
        }
    }
}

// ---------------- causal flash attention, swapped-QK^T MFMA ----------------
// r13 structure (static grid, 2-phase dbuf pipeline, mt-sequential Pl[16])
// + riders: V-pair b32 staging (8 b32 writes vs 16 b16), deferred l-reduce,
// setprio around MFMA clusters. NO launch_bounds floor (r12 lesson).
#define KVBLK 64

__global__ __launch_bounds__(256) void attn_mfma(
        const unsigned short* __restrict__ QKV,
        unsigned short* __restrict__ Yb) {
    __shared__ unsigned short Ks[2][KVBLK][64];  // [key][d], col ^= (key&7)<<3
    __shared__ unsigned short Vt[2][64][KVBLK];  // [d][key], col ^= sig(d)<<3
    __shared__ unsigned short Pl[4][16][64];     // per-wave P[q16][key]

    int t = threadIdx.x;
    int lane = t & 63, wid = t >> 6;
    int l15 = lane & 15, lg = lane >> 4;
    int bh = blockIdx.x;
    int b = bh >> 4, h = bh & 15;
    int by = gridDim.y - 1 - blockIdx.y;   // heavy blocks first
    int qbase = by * 128 + wid * 32;
    int vidx = lg << 4;                    // bpermute byte base: lane lg*4+r

    // K staging geometry (gl_lds): dest byte = t*16 -> row t>>3, chunk t&7;
    // source chunk = (t&7) ^ (row&7)  (inverse of read-side XOR swizzle)
    const int kk1 = t >> 3, kk2 = 32 + kk1;
    const int kg1 = ((t & 7) ^ (kk1 & 7)) << 3;   // element offset
    const int kg2 = ((t & 7) ^ (kk2 & 7)) << 3;
    // V staging geometry (reg, key-pair): keys 2vp,2vp+1 x 8 d, b32 writes
    const int vp2 = (t >> 3) << 1;        // key0 = 2*(t>>3), 0..62
    const int vdc = t & 7;                 // d-chunk 0..7
    const int vd0 = vdc << 3;              // d base 0..56

    const unsigned short* kvbase = QKV + ((size_t)b * S_) * QS + 1024 + h * 64;

    // ---- Q fragments, scale = 1/sqrt(64) * log2(e) (exp2 domain) ----
    const float qscale = 0.125f * 1.44269504f;
    bf16x8 qf[2][2];
#pragma unroll
    for (int mt = 0; mt < 2; ++mt)
#pragma unroll
        for (int ks = 0; ks < 2; ++ks) {
            int row = qbase + mt * 16 + l15;
            bf16x8 v = *(const bf16x8*)&QKV[((size_t)(b * S_ + row)) * QS +
                                            h * 64 + ks * 32 + lg * 8];
#pragma unroll
            for (int e = 0; e < 8; ++e)
                qf[mt][ks][e] = (short)f2b(b2f((unsigned short)v[e]) * qscale);
        }

    f32x4 yacc[2][4] = {};
    float m_[2] = {-1e30f, -1e30f}, l_[2] = {0.f, 0.f};

    int ntiles = by * 2 + 2;

    // ---- prologue: stage tile 0 into buffer 0 ----
    {
        gl_lds16(kvbase + (size_t)kk1 * QS + kg1, &Ks[0][0][0] + (size_t)t * 8);
        gl_lds16(kvbase + (size_t)kk2 * QS + kg2,
                 &Ks[0][0][0] + 2048 + (size_t)t * 8);
        const unsigned short* vsrc = kvbase + 1024 + (size_t)vp2 * QS + vd0;
        bf16x8 v0 = *(const bf16x8*)vsrc;         // key vp2,   d vd0..+7
        bf16x8 v1 = *(const bf16x8*)(vsrc + QS);  // key vp2+1, d vd0..+7
#pragma unroll
        for (int e = 0; e < 8; ++e) {
            int d = vd0 + e;
            int sig = e ^ vdc;                    // (d&7)^((d>>3)&7)
            unsigned u = (unsigned)(unsigned short)v0[e] |
                         ((unsigned)(unsigned short)v1[e] << 16);
            *(unsigned*)&Vt[0][d][vp2 ^ (sig << 3)] = u;
        }
    }
    __syncthreads();   // drains gl_lds (vmcnt) + ds writes

    int cur = 0;
    for (int kt = 0; kt < ntiles; ++kt) {
        int k0 = kt * KVBLK;
        bool pre = (kt + 1 < ntiles);
        bf16x8 nv0, nv1;
        // ---- issue next tile's loads (latency hides under compute) ----
        if (pre) {
            const unsigned short* kb = kvbase + (size_t)(k0 + KVBLK) * QS;
            unsigned short* ld = &Ks[cur ^ 1][0][0];
            gl_lds16(kb + (size_t)kk1 * QS + kg1, ld + (size_t)t * 8);
            gl_lds16(kb + (size_t)kk2 * QS + kg2, ld + 2048 + (size_t)t * 8);
            const unsigned short* vsrc = kb + 1024 + (size_t)vp2 * QS + vd0;
            nv0 = *(const bf16x8*)vsrc;
            nv1 = *(const bf16x8*)(vsrc + QS);
        }

        if (k0 <= qbase + 31) {          // wave not fully masked
            bool boundary = (k0 + KVBLK - 1 > qbase);
            // ---- S^T = K Q^T : rows key (A side), cols q (B side) ----
            f32x4 sacc[2][4] = {};
            __builtin_amdgcn_s_setprio(1);
#pragma unroll
            for (int ks = 0; ks < 2; ++ks) {
                bf16x8 kf[4];
#pragma unroll
                for (int n = 0; n < 4; ++n)
                    kf[n] = *(const bf16x8*)&Ks[cur][n * 16 + l15]
                              [(ks * 32 + lg * 8) ^ ((l15 & 7) << 3)];
#pragma unroll
                for (int mt = 0; mt < 2; ++mt)
#pragma unroll
                    for (int n = 0; n < 4; ++n)
                        sacc[mt][n] = __builtin_amdgcn_mfma_f32_16x16x32_bf16(
                            kf[n], qf[mt][ks], sacc[mt][n], 0, 0, 0);
            }
            __builtin_amdgcn_s_setprio(0);

            // ---- mt SEQUENTIAL: softmax -> pack -> PV per half-tile ----
#pragma unroll
            for (int mt = 0; mt < 2; ++mt) {
                int qv = qbase + mt * 16 + l15;   // this lane's q row
                if (boundary) {
#pragma unroll
                    for (int n = 0; n < 4; ++n)
#pragma unroll
                        for (int r = 0; r < 4; ++r)
                            if (k0 + n * 16 + lg * 4 + r > qv)
                                sacc[mt][n][r] = -3e38f;
                }
                // ---- online softmax over keys (in-reg + 2 shfl) ----
                float pm = -3e38f;
#pragma unroll
                for (int n = 0; n < 4; ++n)
#pragma unroll
                    for (int r = 0; r < 4; ++r)
                        pm = fmaxf(pm, sacc[mt][n][r]);
                pm = fmaxf(pm, __shfl_xor(pm, 16));
                pm = fmaxf(pm, __shfl_xor(pm, 32));
                float mo = m_[mt];
                float mn = mo;
                bool need = __any(pm > mo + 8.0f);   // defer-max THR=8 (exp2)
                if (need) {
                    mn = fmaxf(mo, pm);
                    float corr = __builtin_exp2f(mo - mn);
                    m_[mt] = mn;
                    l_[mt] *= corr;   // per-lane partial (corr uniform per q)
                    int ci = __float_as_int(corr);
#pragma unroll
                    for (int r = 0; r < 4; ++r) {
                        float cq = __int_as_float(
                            __builtin_amdgcn_ds_bpermute(vidx + 4 * r, ci));
#pragma unroll
                        for (int n = 0; n < 4; ++n) yacc[mt][n][r] *= cq;
                    }
                }
                float rs = 0.f;
#pragma unroll
                for (int n = 0; n < 4; ++n)
#pragma unroll
                    for (int r = 0; r < 4; ++r) {
                        float p = __builtin_exp2f(sacc[mt][n][r] - mn);
                        sacc[mt][n][r] = p;
                        rs += p;
                    }
                l_[mt] += rs;   // deferred: cross-lane reduce in epilogue
                // ---- pack P pairs -> per-wave LDS (row q=l15) ----
#pragma unroll
                for (int n = 0; n < 4; ++n)
#pragma unroll
                    for (int j = 0; j < 2; ++j) {
                        unsigned u = cvtpk_bf16(sacc[mt][n][2 * j],
                                                sacc[mt][n][2 * j + 1]);
                        int col = (n * 16 + lg * 4 + 2 * j) ^ ((l15 & 7) << 3);
                        *(unsigned*)&Pl[wid][l15][col] = u;
                    }
                // ---- Y += P V  (16x16x32, A = P from LDS, B = Vt) ----
                __builtin_amdgcn_s_setprio(1);
#pragma unroll
                for (int ks = 0; ks < 2; ++ks) {
                    bf16x8 pa, vf[4];
                    pa = *(const bf16x8*)&Pl[wid][l15]
                           [(ks * 32 + lg * 8) ^ ((l15 & 7) << 3)];
#pragma unroll
                    for (int nd = 0; nd < 4; ++nd) {
                        int d = nd * 16 + l15;
                        int sig = (d & 7) ^ ((d >> 3) & 7);
                        vf[nd] = *(const bf16x8*)&Vt[cur][d]
                                   [(ks * 32 + lg * 8) ^ (sig << 3)];
                    }
#pragma unroll
                    for (int nd = 0; nd < 4; ++nd)
                        yacc[mt][nd] = __builtin_amdgcn_mfma_f32_16x16x32_bf16(
                            pa, vf[nd], yacc[mt][nd], 0, 0, 0);
                }
                __builtin_amdgcn_s_setprio(0);
            }
        }

        // ---- write prefetched V into next buffer (after compute) ----
        if (pre) {
#pragma unroll
            for (int e = 0; e < 8; ++e) {
                int d = vd0 + e;
                int sig = e ^ vdc;
                unsigned u = (unsigned)(unsigned short)nv0[e] |
                             ((unsigned)(unsigned short)nv1[e] << 16);
                *(unsigned*)&Vt[cur ^ 1][d][vp2 ^ (sig << 3)] = u;
            }
        }
        __syncthreads();   // one barrier per tile: drains gl_lds + V writes
        cur ^= 1;
    }

    // ---- epilogue: reduce l across lane-group, write Y / l ----
#pragma unroll
    for (int mt = 0; mt < 2; ++mt) {
        float lt = l_[mt];
        lt += __shfl_xor(lt, 16);
        lt += __shfl_xor(lt, 32);
        float inv = 1.f / lt;
        int ii = __float_as_int(inv);
        float iv[4];
#pragma unroll
        for (int r = 0; r < 4; ++r)
            iv[r] = __int_as_float(
                __builtin_amdgcn_ds_bpermute(vidx + 4 * r, ii));
#pragma unroll
        for (int n = 0; n < 4; ++n)
#pragma unroll
            for (int r = 0; r < 4; ++r) {
                int row = qbase + mt * 16 + lg * 4 + r;
                int d = n * 16 + l15;
                Yb[((size_t)(b * S_ + row)) * E_ + h * 64 + d] =
                    f2b(yacc[mt][n][r] * iv[r]);
            }
    }
}

extern "C" void kernel_launch(void* const* d_in, const int* in_sizes, int n_in,
                              void* d_out, int out_size, void* d_ws, size_t ws_size,
                              hipStream_t stream) {
    const float* x  = (const float*)d_in[0];
    const float* Wq = (const float*)d_in[1];
    const float* bq = (const float*)d_in[2];
    const float* Wk = (const float*)d_in[3];
    const float* bk = (const float*)d_in[4];
    const float* Wv = (const float*)d_in[5];
    const float* bv = (const float*)d_in[6];
    const float* Wo = (const float*)d_in[7];
    const float* bo = (const float*)d_in[8];

    char* ws = (char*)d_ws;
    const size_t M = (size_t)B_ * S_;  // 8192
    unsigned short* xb   = (unsigned short*)ws;                    // 16 MB (reused as Y)
    unsigned short* QKVb = (unsigned short*)(ws + (16ull << 20));  // 48 MB
    unsigned short* Wqkv = (unsigned short*)(ws + (64ull << 20));  // 6 MB
    unsigned short* Wto  = (unsigned short*)(ws + (70ull << 20));  // 2 MB
    unsigned short* Yb   = xb;                                     // reuse

    int n8 = (int)(M * E_ / 8);
    cvt_f32_to_bf16<<<(n8 + 255) / 256, 256, 0, stream>>>(x, xb, n8);

    dim3 tb(32, 8), tg(32, 32, 4);
    transpose_cvt4<<<tg, tb, 0, stream>>>(Wq, Wk, Wv, Wo, Wqkv, Wto);

    // fused QKV projection: C[8192][3072]
    dim3 gq(QS / BN, M / BM);  // (24, 64) = 1536 blocks
    gemm_bt<<<gq, 256, 0, stream>>>(xb, Wqkv, bq, bk, bv, QKVb,
                                    (int)M, QS, E_);

    dim3 ag(B_ * H_, S_ / 128);  // (64, 16)
    attn_mfma<<<ag, 256, 0, stream>>>(QKVb, Yb);

    // output projection: BM=64 tiles -> 1024 blocks
    dim3 gg(E_ / BN, M / 64);  // (8, 128)
    gemm_bt_out<<<gg, 256, 0, stream>>>(Yb, Wto, bo, (float*)d_out,
                                        (int)M, E_, E_);
}

// Round 16
// 195.958 us; speedup vs baseline: 1.1334x; 1.0677x over previous
//
#include <hip/hip_runtime.h>
#include <hip/hip_bf16.h>

#define B_ 4
#define S_ 2048
#define E_ 1024
#define H_ 16
#define HD_ 64
#define QS 3072   // fused QKV row stride

typedef __attribute__((ext_vector_type(8))) short bf16x8;
typedef __attribute__((ext_vector_type(4))) float f32x4;

__device__ __forceinline__ float b2f(unsigned short u) {
    union { unsigned u; float f; } v; v.u = ((unsigned)u) << 16; return v.f;
}
__device__ __forceinline__ unsigned short f2b(float f) {
    union { float f; unsigned u; } v; v.f = f;
    unsigned lsb = (v.u >> 16) & 1u;
    v.u += 0x7fffu + lsb;
    return (unsigned short)(v.u >> 16);
}
__device__ __forceinline__ unsigned cvtpk_bf16(float lo, float hi) {
    unsigned r;
    asm("v_cvt_pk_bf16_f32 %0, %1, %2" : "=v"(r) : "v"(lo), "v"(hi));
    return r;
}

// direct global -> LDS async copy, 16B per lane (linear dest = base + lane*16)
typedef const __attribute__((address_space(1))) unsigned glb_u32;
typedef __attribute__((address_space(3))) unsigned lds_u32;
__device__ __forceinline__ void gl_lds16(const unsigned short* g,
                                         unsigned short* l) {
    __builtin_amdgcn_global_load_lds((glb_u32*)g, (lds_u32*)l, 16, 0, 0);
}

// ---------------- elementwise f32 -> bf16 ----------------
__global__ void cvt_f32_to_bf16(const float* __restrict__ in,
                                unsigned short* __restrict__ out, int n8) {
    int i = blockIdx.x * blockDim.x + threadIdx.x;
    if (i >= n8) return;
    const float4* p = (const float4*)(in + (size_t)i * 8);
    float4 a = p[0], b = p[1];
    bf16x8 o;
    o[0] = (short)f2b(a.x); o[1] = (short)f2b(a.y);
    o[2] = (short)f2b(a.z); o[3] = (short)f2b(a.w);
    o[4] = (short)f2b(b.x); o[5] = (short)f2b(b.y);
    o[6] = (short)f2b(b.z); o[7] = (short)f2b(b.w);
    *(bf16x8*)(out + (size_t)i * 8) = o;
}

// ---------------- 4x W[K][N] f32 -> Wt[N][K] bf16 (one launch) ------------
__global__ void transpose_cvt4(const float* __restrict__ W0,
                               const float* __restrict__ W1,
                               const float* __restrict__ W2,
                               const float* __restrict__ W3,
                               unsigned short* __restrict__ Wqkv,
                               unsigned short* __restrict__ Wto) {
    __shared__ float tile[32][33];
    int z = blockIdx.z;
    const float* W = (z == 0) ? W0 : (z == 1) ? W1 : (z == 2) ? W2 : W3;
    unsigned short* Wt = (z < 3) ? Wqkv + (size_t)z * 1024 * E_ : Wto;
    int tx = threadIdx.x, ty = threadIdx.y;  // (32, 8)
    int x0 = blockIdx.x * 32, y0 = blockIdx.y * 32;
#pragma unroll
    for (int j = 0; j < 32; j += 8)
        tile[ty + j][tx] = W[(size_t)(y0 + ty + j) * E_ + x0 + tx];
    __syncthreads();
#pragma unroll
    for (int j = 0; j < 32; j += 8)
        Wt[(size_t)(x0 + ty + j) * E_ + y0 + tx] = f2b(tile[tx][ty + j]);
}

// ---------------- GEMM: C[M,N] = A[M,K] @ Bt[N,K]^T + bias (bf16 out) -----
// bias selected among b0/b1/b2 by col>>10 (fused-QKV support)
// XCD-aware block swizzle: ti = (bid%8)*chunk + bid/8 (grid %8 == 0)
#define BM 128
#define BN 128
#define BK 32

__global__ __launch_bounds__(256) void gemm_bt(
        const unsigned short* __restrict__ A,
        const unsigned short* __restrict__ Bt,
        const float* __restrict__ b0, const float* __restrict__ b1,
        const float* __restrict__ b2,
        unsigned short* __restrict__ Cb,
        int M, int N, int K) {
    __shared__ unsigned short As[BM][BK];
    __shared__ unsigned short Bs[BN][BK];
    int t = threadIdx.x;
    int lane = t & 63, wid = t >> 6;
    int wr = wid >> 1, wc = wid & 1;
    // XCD swizzle (nwg = gridDim.x*gridDim.y, divisible by 8)
    int nwg = gridDim.x * gridDim.y;
    int bid = blockIdx.y * gridDim.x + blockIdx.x;
    int ti = (bid & 7) * (nwg >> 3) + (bid >> 3);
    int bx = ti % gridDim.x, by = ti / gridDim.x;
    const int row = t >> 2, kc = (t & 3) << 3;
    const unsigned short* ga0 = A + (size_t)(by * BM + row) * K + kc;
    const unsigned short* gb0 = Bt + (size_t)(bx * BN + row) * K + kc;
    unsigned short* la0 = &As[0][0] + (size_t)t * 8;
    unsigned short* lb0 = &Bs[0][0] + (size_t)t * 8;
    const size_t step64 = (size_t)64 * K;

    f32x4 acc[4][4] = {};

    for (int ko = 0; ko < K; ko += BK) {
        gl_lds16(ga0 + ko, la0);
        gl_lds16(ga0 + ko + step64, la0 + 2048);
        gl_lds16(gb0 + ko, lb0);
        gl_lds16(gb0 + ko + step64, lb0 + 2048);
        __syncthreads();   // drains vmcnt(0) -> tiles resident
        int kg = (lane >> 4) << 3;  // k offset 0,8,16,24
        bf16x8 af[4], bfr[4];
#pragma unroll
        for (int i = 0; i < 4; ++i) {
            af[i]  = *(const bf16x8*)&As[wr * 64 + i * 16 + (lane & 15)][kg];
            bfr[i] = *(const bf16x8*)&Bs[wc * 64 + i * 16 + (lane & 15)][kg];
        }
#pragma unroll
        for (int i = 0; i < 4; ++i)
#pragma unroll
            for (int j = 0; j < 4; ++j)
                acc[i][j] = __builtin_amdgcn_mfma_f32_16x16x32_bf16(
                    af[i], bfr[j], acc[i][j], 0, 0, 0);
        __syncthreads();
    }

#pragma unroll
    for (int i = 0; i < 4; ++i) {
        int row0 = by * BM + wr * 64 + i * 16 + ((lane >> 4) << 2);
#pragma unroll
        for (int j = 0; j < 4; ++j) {
            int col = bx * BN + wc * 64 + j * 16 + (lane & 15);
            const float* bp = (col < 1024) ? b0 : ((col < 2048) ? b1 : b2);
            float bv = bp[col & 1023];
#pragma unroll
            for (int r = 0; r < 4; ++r) {
                int rr = row0 + r;
                Cb[(size_t)rr * N + col] = f2b(acc[i][j][r] + bv);
            }
        }
    }
}

// ---------------- output GEMM: BM=64 tile (1024 blocks -> 4+/CU) ----------
__global__ __launch_bounds__(256) void gemm_bt_out(
        const unsigned short* __restrict__ A,
        const unsigned short* __restrict__ Bt,
        const float* __restrict__ bias,
        float* __restrict__ Cf, int M, int N, int K) {
    __shared__ unsigned short As[64][BK];
    __shared__ unsigned short Bs[BN][BK];
    int t = threadIdx.x;
    int lane = t & 63, wid = t >> 6;
    int wr = wid >> 1, wc = wid & 1;   // wave: 32 rows x 64 cols
    int nwg = gridDim.x * gridDim.y;
    int bid = blockIdx.y * gridDim.x + blockIdx.x;
    int ti = (bid & 7) * (nwg >> 3) + (bid >> 3);
    int bx = ti % gridDim.x, by = ti / gridDim.x;
    const int row = t >> 2, kc = (t & 3) << 3;
    const unsigned short* ga0 = A + (size_t)(by * 64 + row) * K + kc;
    const unsigned short* gb0 = Bt + (size_t)(bx * BN + row) * K + kc;
    unsigned short* la0 = &As[0][0] + (size_t)t * 8;
    unsigned short* lb0 = &Bs[0][0] + (size_t)t * 8;
    const size_t step64 = (size_t)64 * K;

    f32x4 acc[2][4] = {};

    for (int ko = 0; ko < K; ko += BK) {
        gl_lds16(ga0 + ko, la0);
        gl_lds16(gb0 + ko, lb0);
        gl_lds16(gb0 + ko + step64, lb0 + 2048);
        __syncthreads();
        int kg = (lane >> 4) << 3;
        bf16x8 af[2], bfr[4];
#pragma unroll
        for (int i = 0; i < 2; ++i)
            af[i] = *(const bf16x8*)&As[wr * 32 + i * 16 + (lane & 15)][kg];
#pragma unroll
        for (int j = 0; j < 4; ++j)
            bfr[j] = *(const bf16x8*)&Bs[wc * 64 + j * 16 + (lane & 15)][kg];
#pragma unroll
        for (int i = 0; i < 2; ++i)
#pragma unroll
            for (int j = 0; j < 4; ++j)
                acc[i][j] = __builtin_amdgcn_mfma_f32_16x16x32_bf16(
                    af[i], bfr[j], acc[i][j], 0, 0, 0);
        __syncthreads();
    }

#pragma unroll
    for (int i = 0; i < 2; ++i) {
        int row0 = by * 64 + wr * 32 + i * 16 + ((lane >> 4) << 2);
#pragma unroll
        for (int j = 0; j < 4; ++j) {
            int col = bx * BN + wc * 64 + j * 16 + (lane & 15);
            float bv = bias[col];
#pragma unroll
            for (int r = 0; r < 4; ++r)
                Cf[(size_t)(row0 + r) * N + col] = acc[i][j][r] + bv;
        }
    }
}

// ---------------- causal flash attention, swapped-QK^T MFMA ----------------
// 8-wave blocks, Q-tile = 256 rows (wave owns 32): staging per q-row HALVES
// vs r13 (1 gl_lds + 1 V-load + 8 ds_writes per thread, 512 threads).
// Wave-level compute identical to proven r13 path (2-phase dbuf pipeline,
// mt-sequential, in-reg softmax w/ defer-max, Pl roundtrip, PV 16x16x32).
#define KVBLK 64

__global__ __launch_bounds__(512) void attn_mfma(
        const unsigned short* __restrict__ QKV,
        unsigned short* __restrict__ Yb) {
    __shared__ unsigned short Ks[2][KVBLK][64];  // [key][d], col ^= (key&7)<<3
    __shared__ unsigned short Vt[2][64][KVBLK];  // [d][key], col ^= sig(d)<<3
    __shared__ unsigned short Pl[8][16][64];     // per-wave P[q16][key]

    int t = threadIdx.x;
    int lane = t & 63, wid = t >> 6;             // wid 0..7
    int l15 = lane & 15, lg = lane >> 4;
    int bh = blockIdx.x;
    int b = bh >> 4, h = bh & 15;
    int by = gridDim.y - 1 - blockIdx.y;         // heavy blocks first, 7..0
    int qbase = by * 256 + wid * 32;
    int vidx = lg << 4;                          // bpermute byte base

    // K staging (gl_lds, 1 load/thread): dest byte = t*16 -> row t>>3, chunk t&7
    // source chunk = (t&7) ^ (row&7)  (inverse of read-side XOR swizzle)
    const int kk = t >> 3;                        // key 0..63
    const int kg = ((t & 7) ^ (kk & 7)) << 3;     // element offset
    // V staging (reg, 1 load/thread): key = t>>3, d-chunk = (t&7)*8
    const int vkey = t >> 3, vc = (t & 7) << 3;

    const unsigned short* kvbase = QKV + ((size_t)b * S_) * QS + 1024 + h * 64;

    // ---- Q fragments, scale = 1/sqrt(64) * log2(e) (exp2 domain) ----
    const float qscale = 0.125f * 1.44269504f;
    bf16x8 qf[2][2];
#pragma unroll
    for (int mt = 0; mt < 2; ++mt)
#pragma unroll
        for (int ks = 0; ks < 2; ++ks) {
            int row = qbase + mt * 16 + l15;
            bf16x8 v = *(const bf16x8*)&QKV[((size_t)(b * S_ + row)) * QS +
                                            h * 64 + ks * 32 + lg * 8];
#pragma unroll
            for (int e = 0; e < 8; ++e)
                qf[mt][ks][e] = (short)f2b(b2f((unsigned short)v[e]) * qscale);
        }

    f32x4 yacc[2][4] = {};
    float m_[2] = {-1e30f, -1e30f}, l_[2] = {0.f, 0.f};

    int ntiles = by * 4 + 4;

    // ---- prologue: stage tile 0 into buffer 0 ----
    {
        gl_lds16(kvbase + (size_t)kk * QS + kg, &Ks[0][0][0] + (size_t)t * 8);
        const unsigned short* vsrc = kvbase + 1024 + (size_t)vkey * QS + vc;
        bf16x8 v0 = *(const bf16x8*)vsrc;
#pragma unroll
        for (int e = 0; e < 8; ++e) {
            int d = vc + e;
            int sig = e ^ (t & 7);               // (d&7)^((d>>3)&7)
            Vt[0][d][vkey ^ (sig << 3)] = (unsigned short)v0[e];
        }
    }
    __syncthreads();   // drains gl_lds (vmcnt) + ds writes

    int cur = 0;
    for (int kt = 0; kt < ntiles; ++kt) {
        int k0 = kt * KVBLK;
        bool pre = (kt + 1 < ntiles);
        bf16x8 nv0;
        // ---- issue next tile's loads (latency hides under compute) ----
        if (pre) {
            const unsigned short* kb = kvbase + (size_t)(k0 + KVBLK) * QS;
            gl_lds16(kb + (size_t)kk * QS + kg,
                     &Ks[cur ^ 1][0][0] + (size_t)t * 8);
            nv0 = *(const bf16x8*)(kb + 1024 + (size_t)vkey * QS + vc);
        }

        if (k0 <= qbase + 31) {          // wave not fully masked
            bool boundary = (k0 + KVBLK - 1 > qbase);
            // ---- S^T = K Q^T : rows key (A side), cols q (B side) ----
            f32x4 sacc[2][4] = {};
#pragma unroll
            for (int ks = 0; ks < 2; ++ks) {
                bf16x8 kf[4];
#pragma unroll
                for (int n = 0; n < 4; ++n)
                    kf[n] = *(const bf16x8*)&Ks[cur][n * 16 + l15]
                              [(ks * 32 + lg * 8) ^ ((l15 & 7) << 3)];
#pragma unroll
                for (int mt = 0; mt < 2; ++mt)
#pragma unroll
                    for (int n = 0; n < 4; ++n)
                        sacc[mt][n] = __builtin_amdgcn_mfma_f32_16x16x32_bf16(
                            kf[n], qf[mt][ks], sacc[mt][n], 0, 0, 0);
            }

            // ---- mt SEQUENTIAL: softmax -> pack -> PV per half-tile ----
#pragma unroll
            for (int mt = 0; mt < 2; ++mt) {
                int qv = qbase + mt * 16 + l15;   // this lane's q row
                if (boundary) {
#pragma unroll
                    for (int n = 0; n < 4; ++n)
#pragma unroll
                        for (int r = 0; r < 4; ++r)
                            if (k0 + n * 16 + lg * 4 + r > qv)
                                sacc[mt][n][r] = -3e38f;
                }
                // ---- online softmax over keys (in-reg + 2 shfl) ----
                float pm = -3e38f;
#pragma unroll
                for (int n = 0; n < 4; ++n)
#pragma unroll
                    for (int r = 0; r < 4; ++r)
                        pm = fmaxf(pm, sacc[mt][n][r]);
                pm = fmaxf(pm, __shfl_xor(pm, 16));
                pm = fmaxf(pm, __shfl_xor(pm, 32));
                float mo = m_[mt];
                float mn = mo;
                bool need = __any(pm > mo + 8.0f);   // defer-max THR=8 (exp2)
                if (need) {
                    mn = fmaxf(mo, pm);
                    float corr = __builtin_exp2f(mo - mn);
                    m_[mt] = mn;
                    l_[mt] *= corr;
                    int ci = __float_as_int(corr);
#pragma unroll
                    for (int r = 0; r < 4; ++r) {
                        float cq = __int_as_float(
                            __builtin_amdgcn_ds_bpermute(vidx + 4 * r, ci));
#pragma unroll
                        for (int n = 0; n < 4; ++n) yacc[mt][n][r] *= cq;
                    }
                }
                float rs = 0.f;
#pragma unroll
                for (int n = 0; n < 4; ++n)
#pragma unroll
                    for (int r = 0; r < 4; ++r) {
                        float p = __builtin_exp2f(sacc[mt][n][r] - mn);
                        sacc[mt][n][r] = p;
                        rs += p;
                    }
                rs += __shfl_xor(rs, 16);
                rs += __shfl_xor(rs, 32);
                l_[mt] += rs;
                // ---- pack P pairs -> per-wave LDS (row q=l15) ----
#pragma unroll
                for (int n = 0; n < 4; ++n)
#pragma unroll
                    for (int j = 0; j < 2; ++j) {
                        unsigned u = cvtpk_bf16(sacc[mt][n][2 * j],
                                                sacc[mt][n][2 * j + 1]);
                        int col = (n * 16 + lg * 4 + 2 * j) ^ ((l15 & 7) << 3);
                        *(unsigned*)&Pl[wid][l15][col] = u;
                    }
                // ---- Y += P V  (16x16x32, A = P from LDS, B = Vt) ----
#pragma unroll
                for (int ks = 0; ks < 2; ++ks) {
                    bf16x8 pa, vf[4];
                    pa = *(const bf16x8*)&Pl[wid][l15]
                           [(ks * 32 + lg * 8) ^ ((l15 & 7) << 3)];
#pragma unroll
                    for (int nd = 0; nd < 4; ++nd) {
                        int d = nd * 16 + l15;
                        int sig = (d & 7) ^ ((d >> 3) & 7);
                        vf[nd] = *(const bf16x8*)&Vt[cur][d]
                                   [(ks * 32 + lg * 8) ^ (sig << 3)];
                    }
#pragma unroll
                    for (int nd = 0; nd < 4; ++nd)
                        yacc[mt][nd] = __builtin_amdgcn_mfma_f32_16x16x32_bf16(
                            pa, vf[nd], yacc[mt][nd], 0, 0, 0);
                }
            }
        }

        // ---- write prefetched V into next buffer (after compute) ----
        if (pre) {
#pragma unroll
            for (int e = 0; e < 8; ++e) {
                int d = vc + e;
                int sig = e ^ (t & 7);
                Vt[cur ^ 1][d][vkey ^ (sig << 3)] = (unsigned short)nv0[e];
            }
        }
        __syncthreads();   // one barrier per tile: drains gl_lds + V writes
        cur ^= 1;
    }

    // ---- epilogue: Y / l  (l lives at lane l15=q; rows need lg*4+r) ----
#pragma unroll
    for (int mt = 0; mt < 2; ++mt) {
        float inv = 1.f / l_[mt];
        int ii = __float_as_int(inv);
        float iv[4];
#pragma unroll
        for (int r = 0; r < 4; ++r)
            iv[r] = __int_as_float(
                __builtin_amdgcn_ds_bpermute(vidx + 4 * r, ii));
#pragma unroll
        for (int n = 0; n < 4; ++n)
#pragma unroll
            for (int r = 0; r < 4; ++r) {
                int row = qbase + mt * 16 + lg * 4 + r;
                int d = n * 16 + l15;
                Yb[((size_t)(b * S_ + row)) * E_ + h * 64 + d] =
                    f2b(yacc[mt][n][r] * iv[r]);
            }
    }
}

extern "C" void kernel_launch(void* const* d_in, const int* in_sizes, int n_in,
                              void* d_out, int out_size, void* d_ws, size_t ws_size,
                              hipStream_t stream) {
    const float* x  = (const float*)d_in[0];
    const float* Wq = (const float*)d_in[1];
    const float* bq = (const float*)d_in[2];
    const float* Wk = (const float*)d_in[3];
    const float* bk = (const float*)d_in[4];
    const float* Wv = (const float*)d_in[5];
    const float* bv = (const float*)d_in[6];
    const float* Wo = (const float*)d_in[7];
    const float* bo = (const float*)d_in[8];

    char* ws = (char*)d_ws;
    const size_t M = (size_t)B_ * S_;  // 8192
    unsigned short* xb   = (unsigned short*)ws;                    // 16 MB (reused as Y)
    unsigned short* QKVb = (unsigned short*)(ws + (16ull << 20));  // 48 MB
    unsigned short* Wqkv = (unsigned short*)(ws + (64ull << 20));  // 6 MB
    unsigned short* Wto  = (unsigned short*)(ws + (70ull << 20));  // 2 MB
    unsigned short* Yb   = xb;                                     // reuse

    int n8 = (int)(M * E_ / 8);
    cvt_f32_to_bf16<<<(n8 + 255) / 256, 256, 0, stream>>>(x, xb, n8);

    dim3 tb(32, 8), tg(32, 32, 4);
    transpose_cvt4<<<tg, tb, 0, stream>>>(Wq, Wk, Wv, Wo, Wqkv, Wto);

    // fused QKV projection: C[8192][3072]
    dim3 gq(QS / BN, M / BM);  // (24, 64) = 1536 blocks
    gemm_bt<<<gq, 256, 0, stream>>>(xb, Wqkv, bq, bk, bv, QKVb,
                                    (int)M, QS, E_);

    // attention: 8-wave blocks, Q-tile 256
    dim3 ag(B_ * H_, S_ / 256);  // (64, 8) = 512 blocks
    attn_mfma<<<ag, 512, 0, stream>>>(QKVb, Yb);

    // output projection: BM=64 tiles -> 1024 blocks
    dim3 gg(E_ / BN, M / 64);  // (8, 128)
    gemm_bt_out<<<gg, 256, 0, stream>>>(Yb, Wto, bo, (float*)d_out,
                                        (int)M, E_, E_);
}

// Round 17
// 185.470 us; speedup vs baseline: 1.1975x; 1.0566x over previous
//
#include <hip/hip_runtime.h>
#include <hip/hip_bf16.h>

#define B_ 4
#define S_ 2048
#define E_ 1024
#define H_ 16
#define HD_ 64
#define QS 3072   // fused QKV row stride

typedef __attribute__((ext_vector_type(8))) short bf16x8;
typedef __attribute__((ext_vector_type(4))) float f32x4;

__device__ __forceinline__ float b2f(unsigned short u) {
    union { unsigned u; float f; } v; v.u = ((unsigned)u) << 16; return v.f;
}
__device__ __forceinline__ unsigned short f2b(float f) {
    union { float f; unsigned u; } v; v.f = f;
    unsigned lsb = (v.u >> 16) & 1u;
    v.u += 0x7fffu + lsb;
    return (unsigned short)(v.u >> 16);
}
__device__ __forceinline__ unsigned cvtpk_bf16(float lo, float hi) {
    unsigned r;
    asm("v_cvt_pk_bf16_f32 %0, %1, %2" : "=v"(r) : "v"(lo), "v"(hi));
    return r;
}

// direct global -> LDS async copy, 16B per lane (linear dest = base + lane*16)
typedef const __attribute__((address_space(1))) unsigned glb_u32;
typedef __attribute__((address_space(3))) unsigned lds_u32;
__device__ __forceinline__ void gl_lds16(const unsigned short* g,
                                         unsigned short* l) {
    __builtin_amdgcn_global_load_lds((glb_u32*)g, (lds_u32*)l, 16, 0, 0);
}

// ---------------- elementwise f32 -> bf16 ----------------
__global__ void cvt_f32_to_bf16(const float* __restrict__ in,
                                unsigned short* __restrict__ out, int n8) {
    int i = blockIdx.x * blockDim.x + threadIdx.x;
    if (i >= n8) return;
    const float4* p = (const float4*)(in + (size_t)i * 8);
    float4 a = p[0], b = p[1];
    bf16x8 o;
    o[0] = (short)f2b(a.x); o[1] = (short)f2b(a.y);
    o[2] = (short)f2b(a.z); o[3] = (short)f2b(a.w);
    o[4] = (short)f2b(b.x); o[5] = (short)f2b(b.y);
    o[6] = (short)f2b(b.z); o[7] = (short)f2b(b.w);
    *(bf16x8*)(out + (size_t)i * 8) = o;
}

// ---------------- 4x W[K][N] f32 -> Wt[N][K] bf16 (one launch) ------------
__global__ void transpose_cvt4(const float* __restrict__ W0,
                               const float* __restrict__ W1,
                               const float* __restrict__ W2,
                               const float* __restrict__ W3,
                               unsigned short* __restrict__ Wqkv,
                               unsigned short* __restrict__ Wto) {
    __shared__ float tile[32][33];
    int z = blockIdx.z;
    const float* W = (z == 0) ? W0 : (z == 1) ? W1 : (z == 2) ? W2 : W3;
    unsigned short* Wt = (z < 3) ? Wqkv + (size_t)z * 1024 * E_ : Wto;
    int tx = threadIdx.x, ty = threadIdx.y;  // (32, 8)
    int x0 = blockIdx.x * 32, y0 = blockIdx.y * 32;
#pragma unroll
    for (int j = 0; j < 32; j += 8)
        tile[ty + j][tx] = W[(size_t)(y0 + ty + j) * E_ + x0 + tx];
    __syncthreads();
#pragma unroll
    for (int j = 0; j < 32; j += 8)
        Wt[(size_t)(x0 + ty + j) * E_ + y0 + tx] = f2b(tile[tx][ty + j]);
}

// ---------------- GEMM: C[M,N] = A[M,K] @ Bt[N,K]^T + bias (bf16 out) -----
// 2-phase double-buffered: stage(t+1) issued BEFORE compute(t), ONE barrier
// per K-step. bias selected among b0/b1/b2 by col>>10 (fused-QKV support).
// XCD-aware block swizzle: ti = (bid%8)*chunk + bid/8 (grid %8 == 0)
#define BM 128
#define BN 128
#define BK 32

__global__ __launch_bounds__(256) void gemm_bt(
        const unsigned short* __restrict__ A,
        const unsigned short* __restrict__ Bt,
        const float* __restrict__ b0, const float* __restrict__ b1,
        const float* __restrict__ b2,
        unsigned short* __restrict__ Cb,
        int M, int N, int K) {
    __shared__ unsigned short As[2][BM][BK];
    __shared__ unsigned short Bs[2][BN][BK];
    int t = threadIdx.x;
    int lane = t & 63, wid = t >> 6;
    int wr = wid >> 1, wc = wid & 1;
    // XCD swizzle (nwg = gridDim.x*gridDim.y, divisible by 8)
    int nwg = gridDim.x * gridDim.y;
    int bid = blockIdx.y * gridDim.x + blockIdx.x;
    int ti = (bid & 7) * (nwg >> 3) + (bid >> 3);
    int bx = ti % gridDim.x, by = ti / gridDim.x;
    const int row = t >> 2, kc = (t & 3) << 3;
    const unsigned short* ga0 = A + (size_t)(by * BM + row) * K + kc;
    const unsigned short* gb0 = Bt + (size_t)(bx * BN + row) * K + kc;
    unsigned short* la0 = &As[0][0][0] + (size_t)t * 8;
    unsigned short* lb0 = &Bs[0][0][0] + (size_t)t * 8;
    const size_t step64 = (size_t)64 * K;

    f32x4 acc[4][4] = {};

    // prologue: stage ko=0 into buffer 0
    gl_lds16(ga0, la0);
    gl_lds16(ga0 + step64, la0 + 2048);
    gl_lds16(gb0, lb0);
    gl_lds16(gb0 + step64, lb0 + 2048);
    __syncthreads();

    int cur = 0;
    for (int ko = 0; ko < K; ko += BK) {
        if (ko + BK < K) {   // issue next K-step's loads before compute
            unsigned short* la = la0 + (cur ^ 1) * (BM * BK);
            unsigned short* lb = lb0 + (cur ^ 1) * (BN * BK);
            gl_lds16(ga0 + ko + BK, la);
            gl_lds16(ga0 + ko + BK + step64, la + 2048);
            gl_lds16(gb0 + ko + BK, lb);
            gl_lds16(gb0 + ko + BK + step64, lb + 2048);
        }
        int kg = (lane >> 4) << 3;  // k offset 0,8,16,24
        bf16x8 af[4], bfr[4];
#pragma unroll
        for (int i = 0; i < 4; ++i) {
            af[i]  = *(const bf16x8*)&As[cur][wr * 64 + i * 16 + (lane & 15)][kg];
            bfr[i] = *(const bf16x8*)&Bs[cur][wc * 64 + i * 16 + (lane & 15)][kg];
        }
#pragma unroll
        for (int i = 0; i < 4; ++i)
#pragma unroll
            for (int j = 0; j < 4; ++j)
                acc[i][j] = __builtin_amdgcn_mfma_f32_16x16x32_bf16(
                    af[i], bfr[j], acc[i][j], 0, 0, 0);
        __syncthreads();   // one barrier: drains prefetch + guards reuse
        cur ^= 1;
    }

#pragma unroll
    for (int i = 0; i < 4; ++i) {
        int row0 = by * BM + wr * 64 + i * 16 + ((lane >> 4) << 2);
#pragma unroll
        for (int j = 0; j < 4; ++j) {
            int col = bx * BN + wc * 64 + j * 16 + (lane & 15);
            const float* bp = (col < 1024) ? b0 : ((col < 2048) ? b1 : b2);
            float bv = bp[col & 1023];
#pragma unroll
            for (int r = 0; r < 4; ++r) {
                int rr = row0 + r;
                Cb[(size_t)rr * N + col] = f2b(acc[i][j][r] + bv);
            }
        }
    }
}

// ---------------- output GEMM: BM=64 tile, 2-phase dbuf -------------------
__global__ __launch_bounds__(256) void gemm_bt_out(
        const unsigned short* __restrict__ A,
        const unsigned short* __restrict__ Bt,
        const float* __restrict__ bias,
        float* __restrict__ Cf, int M, int N, int K) {
    __shared__ unsigned short As[2][64][BK];
    __shared__ unsigned short Bs[2][BN][BK];
    int t = threadIdx.x;
    int lane = t & 63, wid = t >> 6;
    int wr = wid >> 1, wc = wid & 1;   // wave: 32 rows x 64 cols
    int nwg = gridDim.x * gridDim.y;
    int bid = blockIdx.y * gridDim.x + blockIdx.x;
    int ti = (bid & 7) * (nwg >> 3) + (bid >> 3);
    int bx = ti % gridDim.x, by = ti / gridDim.x;
    const int row = t >> 2, kc = (t & 3) << 3;
    const unsigned short* ga0 = A + (size_t)(by * 64 + row) * K + kc;
    const unsigned short* gb0 = Bt + (size_t)(bx * BN + row) * K + kc;
    unsigned short* la0 = &As[0][0][0] + (size_t)t * 8;
    unsigned short* lb0 = &Bs[0][0][0] + (size_t)t * 8;
    const size_t step64 = (size_t)64 * K;

    f32x4 acc[2][4] = {};

    // prologue: stage ko=0 into buffer 0 (A: first 256 lanes' 8-chunks)
    gl_lds16(ga0, la0);
    gl_lds16(gb0, lb0);
    gl_lds16(gb0 + step64, lb0 + 2048);
    __syncthreads();

    int cur = 0;
    for (int ko = 0; ko < K; ko += BK) {
        if (ko + BK < K) {
            unsigned short* la = la0 + (cur ^ 1) * (64 * BK);
            unsigned short* lb = lb0 + (cur ^ 1) * (BN * BK);
            gl_lds16(ga0 + ko + BK, la);
            gl_lds16(gb0 + ko + BK, lb);
            gl_lds16(gb0 + ko + BK + step64, lb + 2048);
        }
        int kg = (lane >> 4) << 3;
        bf16x8 af[2], bfr[4];
#pragma unroll
        for (int i = 0; i < 2; ++i)
            af[i] = *(const bf16x8*)&As[cur][wr * 32 + i * 16 + (lane & 15)][kg];
#pragma unroll
        for (int j = 0; j < 4; ++j)
            bfr[j] = *(const bf16x8*)&Bs[cur][wc * 64 + j * 16 + (lane & 15)][kg];
#pragma unroll
        for (int i = 0; i < 2; ++i)
#pragma unroll
            for (int j = 0; j < 4; ++j)
                acc[i][j] = __builtin_amdgcn_mfma_f32_16x16x32_bf16(
                    af[i], bfr[j], acc[i][j], 0, 0, 0);
        __syncthreads();
        cur ^= 1;
    }

#pragma unroll
    for (int i = 0; i < 2; ++i) {
        int row0 = by * 64 + wr * 32 + i * 16 + ((lane >> 4) << 2);
#pragma unroll
        for (int j = 0; j < 4; ++j) {
            int col = bx * BN + wc * 64 + j * 16 + (lane & 15);
            float bv = bias[col];
#pragma unroll
            for (int r = 0; r < 4; ++r)
                Cf[(size_t)(row0 + r) * N + col] = acc[i][j][r] + bv;
        }
    }
}

// ---------------- causal flash attention, swapped-QK^T MFMA ----------------
// r16-proven: 8-wave blocks, Q-tile 256, 2-phase dbuf pipeline, in-reg
// softmax w/ defer-max, Pl roundtrip, PV 16x16x32.
#define KVBLK 64

__global__ __launch_bounds__(512) void attn_mfma(
        const unsigned short* __restrict__ QKV,
        unsigned short* __restrict__ Yb) {
    __shared__ unsigned short Ks[2][KVBLK][64];  // [key][d], col ^= (key&7)<<3
    __shared__ unsigned short Vt[2][64][KVBLK];  // [d][key], col ^= sig(d)<<3
    __shared__ unsigned short Pl[8][16][64];     // per-wave P[q16][key]

    int t = threadIdx.x;
    int lane = t & 63, wid = t >> 6;             // wid 0..7
    int l15 = lane & 15, lg = lane >> 4;
    int bh = blockIdx.x;
    int b = bh >> 4, h = bh & 15;
    int by = gridDim.y - 1 - blockIdx.y;         // heavy blocks first, 7..0
    int qbase = by * 256 + wid * 32;
    int vidx = lg << 4;                          // bpermute byte base

    // K staging (gl_lds, 1 load/thread): dest byte = t*16 -> row t>>3, chunk t&7
    // source chunk = (t&7) ^ (row&7)  (inverse of read-side XOR swizzle)
    const int kk = t >> 3;                        // key 0..63
    const int kg = ((t & 7) ^ (kk & 7)) << 3;     // element offset
    // V staging (reg, 1 load/thread): key = t>>3, d-chunk = (t&7)*8
    const int vkey = t >> 3, vc = (t & 7) << 3;

    const unsigned short* kvbase = QKV + ((size_t)b * S_) * QS + 1024 + h * 64;

    // ---- Q fragments, scale = 1/sqrt(64) * log2(e) (exp2 domain) ----
    const float qscale = 0.125f * 1.44269504f;
    bf16x8 qf[2][2];
#pragma unroll
    for (int mt = 0; mt < 2; ++mt)
#pragma unroll
        for (int ks = 0; ks < 2; ++ks) {
            int row = qbase + mt * 16 + l15;
            bf16x8 v = *(const bf16x8*)&QKV[((size_t)(b * S_ + row)) * QS +
                                            h * 64 + ks * 32 + lg * 8];
#pragma unroll
            for (int e = 0; e < 8; ++e)
                qf[mt][ks][e] = (short)f2b(b2f((unsigned short)v[e]) * qscale);
        }

    f32x4 yacc[2][4] = {};
    float m_[2] = {-1e30f, -1e30f}, l_[2] = {0.f, 0.f};

    int ntiles = by * 4 + 4;

    // ---- prologue: stage tile 0 into buffer 0 ----
    {
        gl_lds16(kvbase + (size_t)kk * QS + kg, &Ks[0][0][0] + (size_t)t * 8);
        const unsigned short* vsrc = kvbase + 1024 + (size_t)vkey * QS + vc;
        bf16x8 v0 = *(const bf16x8*)vsrc;
#pragma unroll
        for (int e = 0; e < 8; ++e) {
            int d = vc + e;
            int sig = e ^ (t & 7);               // (d&7)^((d>>3)&7)
            Vt[0][d][vkey ^ (sig << 3)] = (unsigned short)v0[e];
        }
    }
    __syncthreads();   // drains gl_lds (vmcnt) + ds writes

    int cur = 0;
    for (int kt = 0; kt < ntiles; ++kt) {
        int k0 = kt * KVBLK;
        bool pre = (kt + 1 < ntiles);
        bf16x8 nv0;
        // ---- issue next tile's loads (latency hides under compute) ----
        if (pre) {
            const unsigned short* kb = kvbase + (size_t)(k0 + KVBLK) * QS;
            gl_lds16(kb + (size_t)kk * QS + kg,
                     &Ks[cur ^ 1][0][0] + (size_t)t * 8);
            nv0 = *(const bf16x8*)(kb + 1024 + (size_t)vkey * QS + vc);
        }

        if (k0 <= qbase + 31) {          // wave not fully masked
            bool boundary = (k0 + KVBLK - 1 > qbase);
            // ---- S^T = K Q^T : rows key (A side), cols q (B side) ----
            f32x4 sacc[2][4] = {};
#pragma unroll
            for (int ks = 0; ks < 2; ++ks) {
                bf16x8 kf[4];
#pragma unroll
                for (int n = 0; n < 4; ++n)
                    kf[n] = *(const bf16x8*)&Ks[cur][n * 16 + l15]
                              [(ks * 32 + lg * 8) ^ ((l15 & 7) << 3)];
#pragma unroll
                for (int mt = 0; mt < 2; ++mt)
#pragma unroll
                    for (int n = 0; n < 4; ++n)
                        sacc[mt][n] = __builtin_amdgcn_mfma_f32_16x16x32_bf16(
                            kf[n], qf[mt][ks], sacc[mt][n], 0, 0, 0);
            }

            // ---- mt SEQUENTIAL: softmax -> pack -> PV per half-tile ----
#pragma unroll
            for (int mt = 0; mt < 2; ++mt) {
                int qv = qbase + mt * 16 + l15;   // this lane's q row
                if (boundary) {
#pragma unroll
                    for (int n = 0; n < 4; ++n)
#pragma unroll
                        for (int r = 0; r < 4; ++r)
                            if (k0 + n * 16 + lg * 4 + r > qv)
                                sacc[mt][n][r] = -3e38f;
                }
                // ---- online softmax over keys (in-reg + 2 shfl) ----
                float pm = -3e38f;
#pragma unroll
                for (int n = 0; n < 4; ++n)
#pragma unroll
                    for (int r = 0; r < 4; ++r)
                        pm = fmaxf(pm, sacc[mt][n][r]);
                pm = fmaxf(pm, __shfl_xor(pm, 16));
                pm = fmaxf(pm, __shfl_xor(pm, 32));
                float mo = m_[mt];
                float mn = mo;
                bool need = __any(pm > mo + 8.0f);   // defer-max THR=8 (exp2)
                if (need) {
                    mn = fmaxf(mo, pm);
                    float corr = __builtin_exp2f(mo - mn);
                    m_[mt] = mn;
                    l_[mt] *= corr;
                    int ci = __float_as_int(corr);
#pragma unroll
                    for (int r = 0; r < 4; ++r) {
                        float cq = __int_as_float(
                            __builtin_amdgcn_ds_bpermute(vidx + 4 * r, ci));
#pragma unroll
                        for (int n = 0; n < 4; ++n) yacc[mt][n][r] *= cq;
                    }
                }
                float rs = 0.f;
#pragma unroll
                for (int n = 0; n < 4; ++n)
#pragma unroll
                    for (int r = 0; r < 4; ++r) {
                        float p = __builtin_exp2f(sacc[mt][n][r] - mn);
                        sacc[mt][n][r] = p;
                        rs += p;
                    }
                rs += __shfl_xor(rs, 16);
                rs += __shfl_xor(rs, 32);
                l_[mt] += rs;
                // ---- pack P pairs -> per-wave LDS (row q=l15) ----
#pragma unroll
                for (int n = 0; n < 4; ++n)
#pragma unroll
                    for (int j = 0; j < 2; ++j) {
                        unsigned u = cvtpk_bf16(sacc[mt][n][2 * j],
                                                sacc[mt][n][2 * j + 1]);
                        int col = (n * 16 + lg * 4 + 2 * j) ^ ((l15 & 7) << 3);
                        *(unsigned*)&Pl[wid][l15][col] = u;
                    }
                // ---- Y += P V  (16x16x32, A = P from LDS, B = Vt) ----
#pragma unroll
                for (int ks = 0; ks < 2; ++ks) {
                    bf16x8 pa, vf[4];
                    pa = *(const bf16x8*)&Pl[wid][l15]
                           [(ks * 32 + lg * 8) ^ ((l15 & 7) << 3)];
#pragma unroll
                    for (int nd = 0; nd < 4; ++nd) {
                        int d = nd * 16 + l15;
                        int sig = (d & 7) ^ ((d >> 3) & 7);
                        vf[nd] = *(const bf16x8*)&Vt[cur][d]
                                   [(ks * 32 + lg * 8) ^ (sig << 3)];
                    }
#pragma unroll
                    for (int nd = 0; nd < 4; ++nd)
                        yacc[mt][nd] = __builtin_amdgcn_mfma_f32_16x16x32_bf16(
                            pa, vf[nd], yacc[mt][nd], 0, 0, 0);
                }
            }
        }

        // ---- write prefetched V into next buffer (after compute) ----
        if (pre) {
#pragma unroll
            for (int e = 0; e < 8; ++e) {
                int d = vc + e;
                int sig = e ^ (t & 7);
                Vt[cur ^ 1][d][vkey ^ (sig << 3)] = (unsigned short)nv0[e];
            }
        }
        __syncthreads();   // one barrier per tile: drains gl_lds + V writes
        cur ^= 1;
    }

    // ---- epilogue: Y / l  (l lives at lane l15=q; rows need lg*4+r) ----
#pragma unroll
    for (int mt = 0; mt < 2; ++mt) {
        float inv = 1.f / l_[mt];
        int ii = __float_as_int(inv);
        float iv[4];
#pragma unroll
        for (int r = 0; r < 4; ++r)
            iv[r] = __int_as_float(
                __builtin_amdgcn_ds_bpermute(vidx + 4 * r, ii));
#pragma unroll
        for (int n = 0; n < 4; ++n)
#pragma unroll
            for (int r = 0; r < 4; ++r) {
                int row = qbase + mt * 16 + lg * 4 + r;
                int d = n * 16 + l15;
                Yb[((size_t)(b * S_ + row)) * E_ + h * 64 + d] =
                    f2b(yacc[mt][n][r] * iv[r]);
            }
    }
}

extern "C" void kernel_launch(void* const* d_in, const int* in_sizes, int n_in,
                              void* d_out, int out_size, void* d_ws, size_t ws_size,
                              hipStream_t stream) {
    const float* x  = (const float*)d_in[0];
    const float* Wq = (const float*)d_in[1];
    const float* bq = (const float*)d_in[2];
    const float* Wk = (const float*)d_in[3];
    const float* bk = (const float*)d_in[4];
    const float* Wv = (const float*)d_in[5];
    const float* bv = (const float*)d_in[6];
    const float* Wo = (const float*)d_in[7];
    const float* bo = (const float*)d_in[8];

    char* ws = (char*)d_ws;
    const size_t M = (size_t)B_ * S_;  // 8192
    unsigned short* xb   = (unsigned short*)ws;                    // 16 MB (reused as Y)
    unsigned short* QKVb = (unsigned short*)(ws + (16ull << 20));  // 48 MB
    unsigned short* Wqkv = (unsigned short*)(ws + (64ull << 20));  // 6 MB
    unsigned short* Wto  = (unsigned short*)(ws + (70ull << 20));  // 2 MB
    unsigned short* Yb   = xb;                                     // reuse

    int n8 = (int)(M * E_ / 8);
    cvt_f32_to_bf16<<<(n8 + 255) / 256, 256, 0, stream>>>(x, xb, n8);

    dim3 tb(32, 8), tg(32, 32, 4);
    transpose_cvt4<<<tg, tb, 0, stream>>>(Wq, Wk, Wv, Wo, Wqkv, Wto);

    // fused QKV projection: C[8192][3072]
    dim3 gq(QS / BN, M / BM);  // (24, 64) = 1536 blocks
    gemm_bt<<<gq, 256, 0, stream>>>(xb, Wqkv, bq, bk, bv, QKVb,
                                    (int)M, QS, E_);

    // attention: 8-wave blocks, Q-tile 256
    dim3 ag(B_ * H_, S_ / 256);  // (64, 8) = 512 blocks
    attn_mfma<<<ag, 512, 0, stream>>>(QKVb, Yb);

    // output projection: BM=64 tiles -> 1024 blocks
    dim3 gg(E_ / BN, M / 64);  // (8, 128)
    gemm_bt_out<<<gg, 256, 0, stream>>>(Yb, Wto, bo, (float*)d_out,
                                        (int)M, E_, E_);
}